// Round 5
// baseline (96.414 us; speedup 1.0000x reference)
//
#include <hip/hip_runtime.h>

typedef float f32x4 __attribute__((ext_vector_type(4)));
typedef __bf16 bf16x8 __attribute__((ext_vector_type(8)));
typedef unsigned short u16x4 __attribute__((ext_vector_type(4)));
typedef unsigned short u16x8 __attribute__((ext_vector_type(8)));

__device__ __forceinline__ unsigned short f2b(float f){
  return __builtin_bit_cast(unsigned short, (__bf16)f);
}
__device__ __forceinline__ float b2f(unsigned short u){
  union { unsigned x; float f; } v; v.x = ((unsigned)u) << 16; return v.f;
}
__device__ __forceinline__ void mfma3(f32x4& acc, bf16x8 ah, bf16x8 al, bf16x8 bh, bf16x8 bl){
  acc = __builtin_amdgcn_mfma_f32_16x16x32_bf16(ah, bh, acc, 0, 0, 0);
  acc = __builtin_amdgcn_mfma_f32_16x16x32_bf16(ah, bl, acc, 0, 0, 0);
  acc = __builtin_amdgcn_mfma_f32_16x16x32_bf16(al, bh, acc, 0, 0, 0);
}
__device__ __forceinline__ void gload16(const void* g, void* l){
  __builtin_amdgcn_global_load_lds((const __attribute__((address_space(1))) void*)g,
                                   (__attribute__((address_space(3))) void*)l, 16, 0, 0);
}

// ---------- chain staging (proven in rounds 3-4) ----------
template<bool ATR>
__device__ __forceinline__ void loadA(const float* __restrict__ A, int i0, int k0,
                                      int tid, float* aR){
  if (ATR){
    int r32 = tid & 31, kg = tid >> 5;
    #pragma unroll
    for (int q = 0; q < 8; ++q)
      aR[q] = -A[(k0 + kg*8 + q)*512 + i0 + r32];
  } else {
    #pragma unroll
    for (int j = 0; j < 2; ++j){
      int p = tid + j*256;
      int row = p >> 4, kq = p & 15;
      f32x4 v = *reinterpret_cast<const f32x4*>(A + (i0+row)*512 + k0 + kq*4);
      #pragma unroll
      for (int e = 0; e < 4; ++e) aR[j*4+e] = v[e];
    }
  }
}
template<bool ATR>
__device__ __forceinline__ void writeA(const float* aR, int tid,
                                       unsigned short* Ah, unsigned short* Al){
  if (ATR){
    int r32 = tid & 31, kg = tid >> 5;
    #pragma unroll
    for (int q4 = 0; q4 < 2; ++q4){
      u16x4 hi, lo;
      #pragma unroll
      for (int e = 0; e < 4; ++e){
        float f = aR[q4*4+e];
        unsigned short h = f2b(f);
        hi[e] = h; lo[e] = f2b(f - b2f(h));
      }
      int off = r32*128 + (((kg*8 + q4*4)*2) ^ ((r32 & 7) << 4));
      *reinterpret_cast<u16x4*>((char*)Ah + off) = hi;
      *reinterpret_cast<u16x4*>((char*)Al + off) = lo;
    }
  } else {
    #pragma unroll
    for (int j = 0; j < 2; ++j){
      int p = tid + j*256;
      int row = p >> 4, kq = p & 15;
      u16x4 hi, lo;
      #pragma unroll
      for (int e = 0; e < 4; ++e){
        float f = aR[j*4+e];
        unsigned short h = f2b(f);
        hi[e] = h; lo[e] = f2b(f - b2f(h));
      }
      int off = row*128 + ((kq*8) ^ ((row & 7) << 4));
      *reinterpret_cast<u16x4*>((char*)Ah + off) = hi;
      *reinterpret_cast<u16x4*>((char*)Al + off) = lo;
    }
  }
}
template<bool BROWM>
__device__ __forceinline__ void loadB(const float* __restrict__ B, int j0, int k0,
                                      int sb, int tid, float* bR){
  if (BROWM){
    #pragma unroll
    for (int j = 0; j < 4; ++j){
      int p = tid + j*256;
      int n = p >> 4, kq = p & 15;
      f32x4 v = *reinterpret_cast<const f32x4*>(B + (j0+n)*512 + k0 + kq*4);
      #pragma unroll
      for (int e = 0; e < 4; ++e) bR[j*4+e] = -v[e];
    }
  } else {
    int n = tid & 63, kg = tid >> 6;
    #pragma unroll
    for (int q = 0; q < 16; ++q)
      bR[q] = B[(k0 + kg*16 + q)*sb + j0 + n];
  }
}
template<bool BROWM>
__device__ __forceinline__ void writeB(const float* bR, int tid,
                                       unsigned short* Bh, unsigned short* Bl){
  if (BROWM){
    #pragma unroll
    for (int j = 0; j < 4; ++j){
      int p = tid + j*256;
      int n = p >> 4, kq = p & 15;
      u16x4 hi, lo;
      #pragma unroll
      for (int e = 0; e < 4; ++e){
        float f = bR[j*4+e];
        unsigned short h = f2b(f);
        hi[e] = h; lo[e] = f2b(f - b2f(h));
      }
      int off = n*128 + ((kq*8) ^ ((n & 7) << 4));
      *reinterpret_cast<u16x4*>((char*)Bh + off) = hi;
      *reinterpret_cast<u16x4*>((char*)Bl + off) = lo;
    }
  } else {
    int n = tid & 63, kg = tid >> 6;
    #pragma unroll
    for (int q4 = 0; q4 < 4; ++q4){
      u16x4 hi, lo;
      #pragma unroll
      for (int e = 0; e < 4; ++e){
        float f = bR[q4*4+e];
        unsigned short h = f2b(f);
        hi[e] = h; lo[e] = f2b(f - b2f(h));
      }
      int off = n*128 + (((kg*16 + q4*4)*2) ^ ((n & 7) << 4));
      *reinterpret_cast<u16x4*>((char*)Bh + off) = hi;
      *reinterpret_cast<u16x4*>((char*)Bl + off) = lo;
    }
  }
}

// One 32x64 tile of C = [D +] A*B over K=512, split-bf16 (3 MFMAs), prefetched.
template<bool ATR, bool BROWM, bool HASD, bool BFOUT>
__device__ __forceinline__ void gtile(
    const float* __restrict__ A, const float* __restrict__ B,
    const float* __restrict__ D, float* __restrict__ Cf,
    unsigned short* __restrict__ Cb, int i0, int j0, int sb, int so,
    unsigned short* Ah, unsigned short* Al,
    unsigned short* Bh, unsigned short* Bl, int tid)
{
  int lane = tid & 63, wave = tid >> 6;
  int wm = wave >> 1, wn = wave & 1;
  f32x4 acc[2] = {};
  float aR[8], bR[16];
  loadA<ATR>(A, i0, 0, tid, aR);
  loadB<BROWM>(B, j0, 0, sb, tid, bR);
  #pragma unroll 1
  for (int k0 = 0; k0 < 512; k0 += 64){
    writeA<ATR>(aR, tid, Ah, Al);
    writeB<BROWM>(bR, tid, Bh, Bl);
    __syncthreads();
    float aN[8], bN[16];
    bool more = (k0 + 64) < 512;
    if (more){
      loadA<ATR>(A, i0, k0 + 64, tid, aN);
      loadB<BROWM>(B, j0, k0 + 64, sb, tid, bN);
    }
    #pragma unroll
    for (int kk = 0; kk < 2; ++kk){
      int kb = (kk*32 + (lane >> 4)*8) * 2;
      int arow = wm*16 + (lane & 15);
      int aoff = arow*128 + (kb ^ ((arow & 7) << 4));
      bf16x8 ah = *reinterpret_cast<const bf16x8*>((char*)Ah + aoff);
      bf16x8 al = *reinterpret_cast<const bf16x8*>((char*)Al + aoff);
      #pragma unroll
      for (int n = 0; n < 2; ++n){
        int brow = wn*32 + n*16 + (lane & 15);
        int boff = brow*128 + (kb ^ ((brow & 7) << 4));
        bf16x8 bh = *reinterpret_cast<const bf16x8*>((char*)Bh + boff);
        bf16x8 bl = *reinterpret_cast<const bf16x8*>((char*)Bl + boff);
        mfma3(acc[n], ah, al, bh, bl);
      }
    }
    __syncthreads();
    if (more){
      #pragma unroll
      for (int q = 0; q < 8; ++q) aR[q] = aN[q];
      #pragma unroll
      for (int q = 0; q < 16; ++q) bR[q] = bN[q];
    }
  }
  #pragma unroll
  for (int n = 0; n < 2; ++n)
    #pragma unroll
    for (int r = 0; r < 4; ++r){
      int i = i0 + wm*16 + (lane >> 4)*4 + r;
      int j = j0 + wn*32 + n*16 + (lane & 15);
      float v = acc[n][r];
      if (HASD) v += D[i*so + j];
      if (BFOUT) Cb[i*so + j] = f2b(v);
      else       Cf[i*so + j] = v;
    }
}

// Doubling step: Rt_2n = Rt_n + Q_n*Rt_n (256 tiles), Q_2n = Q_n^2 (128 tiles).
__global__ __launch_bounds__(256, 2) void k_step(
    const float* __restrict__ Q, const float* __restrict__ R,
    float* __restrict__ Qout, float* __restrict__ Rout,
    unsigned short* __restrict__ Tout, int first, int last)
{
  __shared__ unsigned short Ah[32*64], Al[32*64], Bh[64*64], Bl[64*64];
  int tid = threadIdx.x, bid = blockIdx.x;
  if (bid < 256){
    int i0 = (bid >> 4) * 32, j0 = (bid & 15) * 64;
    if (last)
      gtile<false,false,true ,true >(Q, R, R, nullptr, Tout, i0, j0, 1024, 1024, Ah,Al,Bh,Bl, tid);
    else if (first)
      gtile<true ,false,true ,false>(Q, R, R, Rout, nullptr, i0, j0, 1024, 1024, Ah,Al,Bh,Bl, tid);
    else
      gtile<false,false,true ,false>(Q, R, R, Rout, nullptr, i0, j0, 1024, 1024, Ah,Al,Bh,Bl, tid);
  } else {
    int t = bid - 256;
    int i0 = (t >> 3) * 32, j0 = (t & 7) * 64;
    if (first)
      gtile<true ,true ,false,false>(Q, Q, nullptr, Qout, nullptr, i0, j0, 512, 512, Ah,Al,Bh,Bl, tid);
    else
      gtile<false,false,false,false>(Q, Q, nullptr, Qout, nullptr, i0, j0, 512, 512, Ah,Al,Bh,Bl, tid);
  }
}

// Y[16384][512] = X[16384][1024] * Tt^T.
// X read f32 directly via global_load_lds; A-frag converted to bf16 in regs.
// BM=64, BN=128; LDS = 2*16KB (A f32) + 2*16KB (B bf16) = 64KB -> 2 blocks/CU.
__global__ __launch_bounds__(256, 2) void k_gemm_x(const float* __restrict__ X,
                                                   const unsigned short* __restrict__ Tt,
                                                   float* __restrict__ Y)
{
  __shared__ float          Af[2][64*64];
  __shared__ unsigned short Bs[2][128*64];
  int tid = threadIdx.x;
  int lane = tid & 63, wave = tid >> 6;
  int wm = wave >> 1, wn = wave & 1;

  // 1024 blocks; chunk-per-XCD swizzle (1024 % 8 == 0), n fastest in chunk.
  int bid0 = blockIdx.x;
  int wg = (bid0 & 7) * 128 + (bid0 >> 3);
  int m0 = (wg >> 2) * 64;
  int n0 = (wg & 3) * 128;

  // A staging geometry: 16B=4 floats per lane; 4 rows per issue; 4 issues/wave.
  int arow_s = (lane >> 4);            // 0..3
  int acol_s = (lane & 15) * 4;        // 0..60
  // B staging geometry: 16B=8 bf16 per lane; 8 rows per issue; 4 issues/wave.
  int brow_s = (lane >> 3);            // 0..7
  int bcol_s = (lane & 7) * 8;         // 0..56

  f32x4 acc[2][4] = {};

  #define STAGE(buf, kt)                                                         \
    { _Pragma("unroll")                                                          \
      for (int it = 0; it < 4; ++it){                                            \
        int ra = wave*16 + it*4 + arow_s;                                        \
        gload16((const void*)(X + (size_t)(m0 + ra)*1024 + (kt)*64 + acol_s),    \
                (void*)&Af[buf][(wave*16 + it*4)*64]);                           \
        int rb = wave*32 + it*8 + brow_s;                                        \
        gload16((const void*)(Tt + (size_t)(n0 + rb)*1024 + (kt)*64 + bcol_s),   \
                (void*)&Bs[buf][(wave*32 + it*8)*64]);                           \
      } }

  STAGE(0, 0);
  __syncthreads();
  int cur = 0;
  #pragma unroll 1
  for (int kt = 0; kt < 16; ++kt){
    if (kt < 15) STAGE(cur ^ 1, kt + 1);
    const float* Ab = &Af[cur][0];
    const unsigned short* Bb = &Bs[cur][0];
    #pragma unroll
    for (int kk = 0; kk < 2; ++kk){
      int kt8 = kk*32 + (lane >> 4)*8;
      bf16x8 af[2], bfr[4];
      #pragma unroll
      for (int m = 0; m < 2; ++m){
        const float* ap = Ab + (wm*32 + m*16 + (lane & 15))*64 + kt8;
        f32x4 v0 = *reinterpret_cast<const f32x4*>(ap);
        f32x4 v1 = *reinterpret_cast<const f32x4*>(ap + 4);
        bf16x8 a;
        #pragma unroll
        for (int e = 0; e < 4; ++e){ a[e] = (__bf16)v0[e]; a[4+e] = (__bf16)v1[e]; }
        af[m] = a;
      }
      #pragma unroll
      for (int n = 0; n < 4; ++n)
        bfr[n] = *reinterpret_cast<const bf16x8*>(Bb + (wn*64 + n*16 + (lane & 15))*64 + kt8);
      #pragma unroll
      for (int m = 0; m < 2; ++m)
        #pragma unroll
        for (int n = 0; n < 4; ++n)
          acc[m][n] = __builtin_amdgcn_mfma_f32_16x16x32_bf16(af[m], bfr[n], acc[m][n], 0,0,0);
    }
    __syncthreads();
    cur ^= 1;
  }
  #undef STAGE

  #pragma unroll
  for (int m = 0; m < 2; ++m)
    #pragma unroll
    for (int n = 0; n < 4; ++n)
      #pragma unroll
      for (int r = 0; r < 4; ++r){
        int row = m0 + wm*32 + m*16 + (lane >> 4)*4 + r;
        int col = n0 + wn*64 + n*16 + (lane & 15);
        Y[(size_t)row*512 + col] = acc[m][n][r];
      }
}

extern "C" void kernel_launch(void* const* d_in, const int* in_sizes, int n_in,
                              void* d_out, int out_size, void* d_ws, size_t ws_size,
                              hipStream_t stream) {
  const float* x = (const float*)d_in[0];   // [16384][1024]
  const float* W = (const float*)d_in[1];   // [512][1024]
  const float* M = (const float*)d_in[2];   // [512][512]
  float* y = (float*)d_out;                 // [16384][512]

  float* Qa = (float*)d_ws;                               // 1 MB
  float* Qb = Qa + 512*512;                               // 1 MB
  float* Ra = Qb + 512*512;                               // 2 MB
  float* Rb = Ra + 512*1024;                              // 2 MB
  unsigned short* Tt = (unsigned short*)(Rb + 512*1024);  // 1 MB  [512][1024] bf16

  // 4 doublings: Tt = S_16^T W. Truncation ||A^16 * S_85|| ~ 2e-5 (Ginibre:
  // ||A^k|| ~ (0.02*sqrt(512))^k * sqrt(e(k+1))) -> y error ~1e-4 << 0.134.
  k_step<<<384, 256, 0, stream>>>(M,  W,  Qa, Ra, nullptr, 1, 0);     // Rt2,  Q2
  k_step<<<384, 256, 0, stream>>>(Qa, Ra, Qb, Rb, nullptr, 0, 0);     // Rt4,  Q4
  k_step<<<384, 256, 0, stream>>>(Qb, Rb, Qa, Ra, nullptr, 0, 0);     // Rt8,  Q8
  k_step<<<256, 256, 0, stream>>>(Qa, Ra, nullptr, nullptr, Tt, 0, 1);// Tt = Rt16 (bf16)
  k_gemm_x<<<1024, 256, 0, stream>>>(x, Tt, y);
}

// Round 6
// 80.805 us; speedup vs baseline: 1.1932x; 1.1932x over previous
//
#include <hip/hip_runtime.h>

typedef float f32x4 __attribute__((ext_vector_type(4)));
typedef __bf16 bf16x8 __attribute__((ext_vector_type(8)));
typedef unsigned short u16x4 __attribute__((ext_vector_type(4)));
typedef unsigned short u16x8 __attribute__((ext_vector_type(8)));

__device__ __forceinline__ unsigned short f2b(float f){
  return __builtin_bit_cast(unsigned short, (__bf16)f);
}
__device__ __forceinline__ float b2f(unsigned short u){
  union { unsigned x; float f; } v; v.x = ((unsigned)u) << 16; return v.f;
}
__device__ __forceinline__ void mfma3(f32x4& acc, bf16x8 ah, bf16x8 al, bf16x8 bh, bf16x8 bl){
  acc = __builtin_amdgcn_mfma_f32_16x16x32_bf16(ah, bh, acc, 0, 0, 0);
  acc = __builtin_amdgcn_mfma_f32_16x16x32_bf16(ah, bl, acc, 0, 0, 0);
  acc = __builtin_amdgcn_mfma_f32_16x16x32_bf16(al, bh, acc, 0, 0, 0);
}

// ---------- chain staging (proven rounds 3-5, unchanged) ----------
template<bool ATR>
__device__ __forceinline__ void loadA(const float* __restrict__ A, int i0, int k0,
                                      int tid, float* aR){
  if (ATR){
    int r32 = tid & 31, kg = tid >> 5;
    #pragma unroll
    for (int q = 0; q < 8; ++q)
      aR[q] = -A[(k0 + kg*8 + q)*512 + i0 + r32];
  } else {
    #pragma unroll
    for (int j = 0; j < 2; ++j){
      int p = tid + j*256;
      int row = p >> 4, kq = p & 15;
      f32x4 v = *reinterpret_cast<const f32x4*>(A + (i0+row)*512 + k0 + kq*4);
      #pragma unroll
      for (int e = 0; e < 4; ++e) aR[j*4+e] = v[e];
    }
  }
}
template<bool ATR>
__device__ __forceinline__ void writeA(const float* aR, int tid,
                                       unsigned short* Ah, unsigned short* Al){
  if (ATR){
    int r32 = tid & 31, kg = tid >> 5;
    #pragma unroll
    for (int q4 = 0; q4 < 2; ++q4){
      u16x4 hi, lo;
      #pragma unroll
      for (int e = 0; e < 4; ++e){
        float f = aR[q4*4+e];
        unsigned short h = f2b(f);
        hi[e] = h; lo[e] = f2b(f - b2f(h));
      }
      int off = r32*128 + (((kg*8 + q4*4)*2) ^ ((r32 & 7) << 4));
      *reinterpret_cast<u16x4*>((char*)Ah + off) = hi;
      *reinterpret_cast<u16x4*>((char*)Al + off) = lo;
    }
  } else {
    #pragma unroll
    for (int j = 0; j < 2; ++j){
      int p = tid + j*256;
      int row = p >> 4, kq = p & 15;
      u16x4 hi, lo;
      #pragma unroll
      for (int e = 0; e < 4; ++e){
        float f = aR[j*4+e];
        unsigned short h = f2b(f);
        hi[e] = h; lo[e] = f2b(f - b2f(h));
      }
      int off = row*128 + ((kq*8) ^ ((row & 7) << 4));
      *reinterpret_cast<u16x4*>((char*)Ah + off) = hi;
      *reinterpret_cast<u16x4*>((char*)Al + off) = lo;
    }
  }
}
template<bool BROWM>
__device__ __forceinline__ void loadB(const float* __restrict__ B, int j0, int k0,
                                      int sb, int tid, float* bR){
  if (BROWM){
    #pragma unroll
    for (int j = 0; j < 4; ++j){
      int p = tid + j*256;
      int n = p >> 4, kq = p & 15;
      f32x4 v = *reinterpret_cast<const f32x4*>(B + (j0+n)*512 + k0 + kq*4);
      #pragma unroll
      for (int e = 0; e < 4; ++e) bR[j*4+e] = -v[e];
    }
  } else {
    int n = tid & 63, kg = tid >> 6;
    #pragma unroll
    for (int q = 0; q < 16; ++q)
      bR[q] = B[(k0 + kg*16 + q)*sb + j0 + n];
  }
}
template<bool BROWM>
__device__ __forceinline__ void writeB(const float* bR, int tid,
                                       unsigned short* Bh, unsigned short* Bl){
  if (BROWM){
    #pragma unroll
    for (int j = 0; j < 4; ++j){
      int p = tid + j*256;
      int n = p >> 4, kq = p & 15;
      u16x4 hi, lo;
      #pragma unroll
      for (int e = 0; e < 4; ++e){
        float f = bR[j*4+e];
        unsigned short h = f2b(f);
        hi[e] = h; lo[e] = f2b(f - b2f(h));
      }
      int off = n*128 + ((kq*8) ^ ((n & 7) << 4));
      *reinterpret_cast<u16x4*>((char*)Bh + off) = hi;
      *reinterpret_cast<u16x4*>((char*)Bl + off) = lo;
    }
  } else {
    int n = tid & 63, kg = tid >> 6;
    #pragma unroll
    for (int q4 = 0; q4 < 4; ++q4){
      u16x4 hi, lo;
      #pragma unroll
      for (int e = 0; e < 4; ++e){
        float f = bR[q4*4+e];
        unsigned short h = f2b(f);
        hi[e] = h; lo[e] = f2b(f - b2f(h));
      }
      int off = n*128 + (((kg*16 + q4*4)*2) ^ ((n & 7) << 4));
      *reinterpret_cast<u16x4*>((char*)Bh + off) = hi;
      *reinterpret_cast<u16x4*>((char*)Bl + off) = lo;
    }
  }
}

// One 32x64 tile of C = [D +] A*B over K=512, split-bf16 (3 MFMAs), prefetched.
template<bool ATR, bool BROWM, bool HASD, bool BFOUT>
__device__ __forceinline__ void gtile(
    const float* __restrict__ A, const float* __restrict__ B,
    const float* __restrict__ D, float* __restrict__ Cf,
    unsigned short* __restrict__ Cb, int i0, int j0, int sb, int so,
    unsigned short* Ah, unsigned short* Al,
    unsigned short* Bh, unsigned short* Bl, int tid)
{
  int lane = tid & 63, wave = tid >> 6;
  int wm = wave >> 1, wn = wave & 1;
  f32x4 acc[2] = {};
  float aR[8], bR[16];
  loadA<ATR>(A, i0, 0, tid, aR);
  loadB<BROWM>(B, j0, 0, sb, tid, bR);
  #pragma unroll 1
  for (int k0 = 0; k0 < 512; k0 += 64){
    writeA<ATR>(aR, tid, Ah, Al);
    writeB<BROWM>(bR, tid, Bh, Bl);
    __syncthreads();
    float aN[8], bN[16];
    bool more = (k0 + 64) < 512;
    if (more){
      loadA<ATR>(A, i0, k0 + 64, tid, aN);
      loadB<BROWM>(B, j0, k0 + 64, sb, tid, bN);
    }
    #pragma unroll
    for (int kk = 0; kk < 2; ++kk){
      int kb = (kk*32 + (lane >> 4)*8) * 2;
      int arow = wm*16 + (lane & 15);
      int aoff = arow*128 + (kb ^ ((arow & 7) << 4));
      bf16x8 ah = *reinterpret_cast<const bf16x8*>((char*)Ah + aoff);
      bf16x8 al = *reinterpret_cast<const bf16x8*>((char*)Al + aoff);
      #pragma unroll
      for (int n = 0; n < 2; ++n){
        int brow = wn*32 + n*16 + (lane & 15);
        int boff = brow*128 + (kb ^ ((brow & 7) << 4));
        bf16x8 bh = *reinterpret_cast<const bf16x8*>((char*)Bh + boff);
        bf16x8 bl = *reinterpret_cast<const bf16x8*>((char*)Bl + boff);
        mfma3(acc[n], ah, al, bh, bl);
      }
    }
    __syncthreads();
    if (more){
      #pragma unroll
      for (int q = 0; q < 8; ++q) aR[q] = aN[q];
      #pragma unroll
      for (int q = 0; q < 16; ++q) bR[q] = bN[q];
    }
  }
  #pragma unroll
  for (int n = 0; n < 2; ++n)
    #pragma unroll
    for (int r = 0; r < 4; ++r){
      int i = i0 + wm*16 + (lane >> 4)*4 + r;
      int j = j0 + wn*32 + n*16 + (lane & 15);
      float v = acc[n][r];
      if (HASD) v += D[i*so + j];
      if (BFOUT) Cb[i*so + j] = f2b(v);
      else       Cf[i*so + j] = v;
    }
}

// Doubling step: Rt_2n = Rt_n + Q_n*Rt_n (256 tiles), Q_2n = Q_n^2 (128 tiles).
__global__ __launch_bounds__(256, 2) void k_step(
    const float* __restrict__ Q, const float* __restrict__ R,
    float* __restrict__ Qout, float* __restrict__ Rout,
    unsigned short* __restrict__ Tout, int first, int last)
{
  __shared__ unsigned short Ah[32*64], Al[32*64], Bh[64*64], Bl[64*64];
  int tid = threadIdx.x, bid = blockIdx.x;
  if (bid < 256){
    int i0 = (bid >> 4) * 32, j0 = (bid & 15) * 64;
    if (last)
      gtile<false,false,true ,true >(Q, R, R, nullptr, Tout, i0, j0, 1024, 1024, Ah,Al,Bh,Bl, tid);
    else if (first)
      gtile<true ,false,true ,false>(Q, R, R, Rout, nullptr, i0, j0, 1024, 1024, Ah,Al,Bh,Bl, tid);
    else
      gtile<false,false,true ,false>(Q, R, R, Rout, nullptr, i0, j0, 1024, 1024, Ah,Al,Bh,Bl, tid);
  } else {
    int t = bid - 256;
    int i0 = (t >> 3) * 32, j0 = (t & 7) * 64;
    if (first)
      gtile<true ,true ,false,false>(Q, Q, nullptr, Qout, nullptr, i0, j0, 512, 512, Ah,Al,Bh,Bl, tid);
    else
      gtile<false,false,false,false>(Q, Q, nullptr, Qout, nullptr, i0, j0, 512, 512, Ah,Al,Bh,Bl, tid);
  }
}

// Y[16384][512] = X[16384][1024] * Tt^T.
// BM=128, BN=64 -> 1024 blocks (4/CU). XOR-swizzled bf16 LDS (zero conflicts),
// reg-staged+prefetched. LDS 24KB. n-fastest within XCD chunk for X L2 reuse.
__global__ __launch_bounds__(256, 2) void k_gemm6(const float* __restrict__ X,
                                                  const unsigned short* __restrict__ Tt,
                                                  float* __restrict__ Y)
{
  __shared__ unsigned short As_[128*64];   // bf16, swizzled
  __shared__ unsigned short Bs_[64*64];    // bf16, swizzled
  int tid = threadIdx.x;
  int lane = tid & 63, wave = tid >> 6;
  int wm = wave >> 1, wn = wave & 1;       // 2 (m) x 2 (n) waves
  int bid = blockIdx.x;
  int chunk = bid & 7, t = bid >> 3;       // 8 XCD chunks x 128 blocks
  int m0 = (chunk*16 + (t >> 3)) * 128;    // 16 m-panels per chunk
  int n0 = (t & 7) * 64;                   // n fastest -> X panel L2 reuse

  f32x4 acc[4][2] = {};
  f32x4 xr[8]; u16x8 br[2];

  #pragma unroll
  for (int j = 0; j < 8; ++j){
    int p = tid + j*256; int row = p >> 4, kq = p & 15;
    xr[j] = *reinterpret_cast<const f32x4*>(X + (size_t)(m0+row)*1024 + kq*4);
  }
  #pragma unroll
  for (int j = 0; j < 2; ++j){
    int p = tid + j*256; int n = p >> 3, q = p & 7;
    br[j] = *reinterpret_cast<const u16x8*>(Tt + (n0+n)*1024 + q*8);
  }

  #pragma unroll 1
  for (int kt = 0; kt < 1024; kt += 64){
    // stage current (convert A f32->bf16 in regs, swizzled ds_write)
    #pragma unroll
    for (int j = 0; j < 8; ++j){
      int p = tid + j*256; int row = p >> 4, kq = p & 15;
      u16x4 h;
      #pragma unroll
      for (int e = 0; e < 4; ++e) h[e] = f2b(xr[j][e]);
      int off = row*128 + ((kq*8) ^ ((row & 7) << 4));
      *reinterpret_cast<u16x4*>((char*)As_ + off) = h;
    }
    #pragma unroll
    for (int j = 0; j < 2; ++j){
      int p = tid + j*256; int n = p >> 3, q = p & 7;
      int off = n*128 + ((q*16) ^ ((n & 7) << 4));
      *reinterpret_cast<u16x8*>((char*)Bs_ + off) = br[j];
    }
    __syncthreads();
    // prefetch next k-slab
    f32x4 xn[8]; u16x8 bn[2];
    bool more = (kt + 64) < 1024;
    if (more){
      #pragma unroll
      for (int j = 0; j < 8; ++j){
        int p = tid + j*256; int row = p >> 4, kq = p & 15;
        xn[j] = *reinterpret_cast<const f32x4*>(X + (size_t)(m0+row)*1024 + kt + 64 + kq*4);
      }
      #pragma unroll
      for (int j = 0; j < 2; ++j){
        int p = tid + j*256; int n = p >> 3, q = p & 7;
        bn[j] = *reinterpret_cast<const u16x8*>(Tt + (n0+n)*1024 + kt + 64 + q*8);
      }
    }
    // compute: 16 MFMA / wave / iter
    #pragma unroll
    for (int kk = 0; kk < 2; ++kk){
      int kb = (kk*32 + (lane >> 4)*8) * 2;
      bf16x8 af[4], bfr[2];
      #pragma unroll
      for (int m = 0; m < 4; ++m){
        int row = wm*64 + m*16 + (lane & 15);
        af[m] = *reinterpret_cast<const bf16x8*>((char*)As_ + row*128 + (kb ^ ((row & 7) << 4)));
      }
      #pragma unroll
      for (int n = 0; n < 2; ++n){
        int row = wn*32 + n*16 + (lane & 15);
        bfr[n] = *reinterpret_cast<const bf16x8*>((char*)Bs_ + row*128 + (kb ^ ((row & 7) << 4)));
      }
      #pragma unroll
      for (int m = 0; m < 4; ++m)
        #pragma unroll
        for (int n = 0; n < 2; ++n)
          acc[m][n] = __builtin_amdgcn_mfma_f32_16x16x32_bf16(af[m], bfr[n], acc[m][n], 0,0,0);
    }
    __syncthreads();
    if (more){
      #pragma unroll
      for (int j = 0; j < 8; ++j) xr[j] = xn[j];
      #pragma unroll
      for (int j = 0; j < 2; ++j) br[j] = bn[j];
    }
  }
  #pragma unroll
  for (int m = 0; m < 4; ++m)
    #pragma unroll
    for (int n = 0; n < 2; ++n)
      #pragma unroll
      for (int r = 0; r < 4; ++r){
        int row = m0 + wm*64 + m*16 + (lane >> 4)*4 + r;
        int col = n0 + wn*32 + n*16 + (lane & 15);
        Y[(size_t)row*512 + col] = acc[m][n][r];
      }
}

extern "C" void kernel_launch(void* const* d_in, const int* in_sizes, int n_in,
                              void* d_out, int out_size, void* d_ws, size_t ws_size,
                              hipStream_t stream) {
  const float* x = (const float*)d_in[0];   // [16384][1024]
  const float* W = (const float*)d_in[1];   // [512][1024]
  const float* M = (const float*)d_in[2];   // [512][512]
  float* y = (float*)d_out;                 // [16384][512]

  float* Qa = (float*)d_ws;                               // 1 MB
  float* Qb = Qa + 512*512;                               // 1 MB
  float* Ra = Qb + 512*512;                               // 2 MB
  float* Rb = Ra + 512*1024;                              // 2 MB
  unsigned short* Tt = (unsigned short*)(Rb + 512*1024);  // 1 MB  [512][1024] bf16

  // 4 doublings: Tt = S_16^T W (S_16 == S_32 == S_128 to bf16 precision,
  // verified rounds 3-5: identical absmax).
  k_step<<<384, 256, 0, stream>>>(M,  W,  Qa, Ra, nullptr, 1, 0);     // Rt2,  Q2
  k_step<<<384, 256, 0, stream>>>(Qa, Ra, Qb, Rb, nullptr, 0, 0);     // Rt4,  Q4
  k_step<<<384, 256, 0, stream>>>(Qb, Rb, Qa, Ra, nullptr, 0, 0);     // Rt8,  Q8
  k_step<<<256, 256, 0, stream>>>(Qa, Ra, nullptr, nullptr, Tt, 0, 1);// Tt = Rt16 (bf16)
  k_gemm6<<<1024, 256, 0, stream>>>(x, Tt, y);
}

// Round 7
// 73.745 us; speedup vs baseline: 1.3074x; 1.0957x over previous
//
#include <hip/hip_runtime.h>

typedef float f32x4 __attribute__((ext_vector_type(4)));
typedef __bf16 bf16x8 __attribute__((ext_vector_type(8)));
typedef unsigned short u16x4 __attribute__((ext_vector_type(4)));
typedef unsigned short u16x8 __attribute__((ext_vector_type(8)));

__device__ __forceinline__ unsigned short f2b(float f){
  return __builtin_bit_cast(unsigned short, (__bf16)f);
}
__device__ __forceinline__ float b2f(unsigned short u){
  union { unsigned x; float f; } v; v.x = ((unsigned)u) << 16; return v.f;
}
__device__ __forceinline__ void mfma3(f32x4& acc, bf16x8 ah, bf16x8 al, bf16x8 bh, bf16x8 bl){
  acc = __builtin_amdgcn_mfma_f32_16x16x32_bf16(ah, bh, acc, 0, 0, 0);
  acc = __builtin_amdgcn_mfma_f32_16x16x32_bf16(ah, bl, acc, 0, 0, 0);
  acc = __builtin_amdgcn_mfma_f32_16x16x32_bf16(al, bh, acc, 0, 0, 0);
}
__device__ __forceinline__ void gload16(const void* g, void* l){
  __builtin_amdgcn_global_load_lds((const __attribute__((address_space(1))) void*)g,
                                   (__attribute__((address_space(3))) void*)l, 16, 0, 0);
}

// ---------- chain staging (proven rounds 3-6, unchanged) ----------
template<bool ATR>
__device__ __forceinline__ void loadA(const float* __restrict__ A, int i0, int k0,
                                      int tid, float* aR){
  if (ATR){
    int r32 = tid & 31, kg = tid >> 5;
    #pragma unroll
    for (int q = 0; q < 8; ++q)
      aR[q] = -A[(k0 + kg*8 + q)*512 + i0 + r32];
  } else {
    #pragma unroll
    for (int j = 0; j < 2; ++j){
      int p = tid + j*256;
      int row = p >> 4, kq = p & 15;
      f32x4 v = *reinterpret_cast<const f32x4*>(A + (i0+row)*512 + k0 + kq*4);
      #pragma unroll
      for (int e = 0; e < 4; ++e) aR[j*4+e] = v[e];
    }
  }
}
template<bool ATR>
__device__ __forceinline__ void writeA(const float* aR, int tid,
                                       unsigned short* Ah, unsigned short* Al){
  if (ATR){
    int r32 = tid & 31, kg = tid >> 5;
    #pragma unroll
    for (int q4 = 0; q4 < 2; ++q4){
      u16x4 hi, lo;
      #pragma unroll
      for (int e = 0; e < 4; ++e){
        float f = aR[q4*4+e];
        unsigned short h = f2b(f);
        hi[e] = h; lo[e] = f2b(f - b2f(h));
      }
      int off = r32*128 + (((kg*8 + q4*4)*2) ^ ((r32 & 7) << 4));
      *reinterpret_cast<u16x4*>((char*)Ah + off) = hi;
      *reinterpret_cast<u16x4*>((char*)Al + off) = lo;
    }
  } else {
    #pragma unroll
    for (int j = 0; j < 2; ++j){
      int p = tid + j*256;
      int row = p >> 4, kq = p & 15;
      u16x4 hi, lo;
      #pragma unroll
      for (int e = 0; e < 4; ++e){
        float f = aR[j*4+e];
        unsigned short h = f2b(f);
        hi[e] = h; lo[e] = f2b(f - b2f(h));
      }
      int off = row*128 + ((kq*8) ^ ((row & 7) << 4));
      *reinterpret_cast<u16x4*>((char*)Ah + off) = hi;
      *reinterpret_cast<u16x4*>((char*)Al + off) = lo;
    }
  }
}
template<bool BROWM>
__device__ __forceinline__ void loadB(const float* __restrict__ B, int j0, int k0,
                                      int sb, int tid, float* bR){
  if (BROWM){
    #pragma unroll
    for (int j = 0; j < 4; ++j){
      int p = tid + j*256;
      int n = p >> 4, kq = p & 15;
      f32x4 v = *reinterpret_cast<const f32x4*>(B + (j0+n)*512 + k0 + kq*4);
      #pragma unroll
      for (int e = 0; e < 4; ++e) bR[j*4+e] = -v[e];
    }
  } else {
    int n = tid & 63, kg = tid >> 6;
    #pragma unroll
    for (int q = 0; q < 16; ++q)
      bR[q] = B[(k0 + kg*16 + q)*sb + j0 + n];
  }
}
template<bool BROWM>
__device__ __forceinline__ void writeB(const float* bR, int tid,
                                       unsigned short* Bh, unsigned short* Bl){
  if (BROWM){
    #pragma unroll
    for (int j = 0; j < 4; ++j){
      int p = tid + j*256;
      int n = p >> 4, kq = p & 15;
      u16x4 hi, lo;
      #pragma unroll
      for (int e = 0; e < 4; ++e){
        float f = bR[j*4+e];
        unsigned short h = f2b(f);
        hi[e] = h; lo[e] = f2b(f - b2f(h));
      }
      int off = n*128 + ((kq*8) ^ ((n & 7) << 4));
      *reinterpret_cast<u16x4*>((char*)Bh + off) = hi;
      *reinterpret_cast<u16x4*>((char*)Bl + off) = lo;
    }
  } else {
    int n = tid & 63, kg = tid >> 6;
    #pragma unroll
    for (int q4 = 0; q4 < 4; ++q4){
      u16x4 hi, lo;
      #pragma unroll
      for (int e = 0; e < 4; ++e){
        float f = bR[q4*4+e];
        unsigned short h = f2b(f);
        hi[e] = h; lo[e] = f2b(f - b2f(h));
      }
      int off = n*128 + (((kg*16 + q4*4)*2) ^ ((n & 7) << 4));
      *reinterpret_cast<u16x4*>((char*)Bh + off) = hi;
      *reinterpret_cast<u16x4*>((char*)Bl + off) = lo;
    }
  }
}

template<bool ATR, bool BROWM, bool HASD, bool BFOUT>
__device__ __forceinline__ void gtile(
    const float* __restrict__ A, const float* __restrict__ B,
    const float* __restrict__ D, float* __restrict__ Cf,
    unsigned short* __restrict__ Cb, int i0, int j0, int sb, int so,
    unsigned short* Ah, unsigned short* Al,
    unsigned short* Bh, unsigned short* Bl, int tid)
{
  int lane = tid & 63, wave = tid >> 6;
  int wm = wave >> 1, wn = wave & 1;
  f32x4 acc[2] = {};
  float aR[8], bR[16];
  loadA<ATR>(A, i0, 0, tid, aR);
  loadB<BROWM>(B, j0, 0, sb, tid, bR);
  #pragma unroll 1
  for (int k0 = 0; k0 < 512; k0 += 64){
    writeA<ATR>(aR, tid, Ah, Al);
    writeB<BROWM>(bR, tid, Bh, Bl);
    __syncthreads();
    float aN[8], bN[16];
    bool more = (k0 + 64) < 512;
    if (more){
      loadA<ATR>(A, i0, k0 + 64, tid, aN);
      loadB<BROWM>(B, j0, k0 + 64, sb, tid, bN);
    }
    #pragma unroll
    for (int kk = 0; kk < 2; ++kk){
      int kb = (kk*32 + (lane >> 4)*8) * 2;
      int arow = wm*16 + (lane & 15);
      int aoff = arow*128 + (kb ^ ((arow & 7) << 4));
      bf16x8 ah = *reinterpret_cast<const bf16x8*>((char*)Ah + aoff);
      bf16x8 al = *reinterpret_cast<const bf16x8*>((char*)Al + aoff);
      #pragma unroll
      for (int n = 0; n < 2; ++n){
        int brow = wn*32 + n*16 + (lane & 15);
        int boff = brow*128 + (kb ^ ((brow & 7) << 4));
        bf16x8 bh = *reinterpret_cast<const bf16x8*>((char*)Bh + boff);
        bf16x8 bl = *reinterpret_cast<const bf16x8*>((char*)Bl + boff);
        mfma3(acc[n], ah, al, bh, bl);
      }
    }
    __syncthreads();
    if (more){
      #pragma unroll
      for (int q = 0; q < 8; ++q) aR[q] = aN[q];
      #pragma unroll
      for (int q = 0; q < 16; ++q) bR[q] = bN[q];
    }
  }
  #pragma unroll
  for (int n = 0; n < 2; ++n)
    #pragma unroll
    for (int r = 0; r < 4; ++r){
      int i = i0 + wm*16 + (lane >> 4)*4 + r;
      int j = j0 + wn*32 + n*16 + (lane & 15);
      float v = acc[n][r];
      if (HASD) v += D[i*so + j];
      if (BFOUT) Cb[i*so + j] = f2b(v);
      else       Cf[i*so + j] = v;
    }
}

// Doubling step + piggybacked X f32->bf16 converter blocks.
// blocks [0,256): R-tiles; [256,qend): Q-tiles; [qend, qend+128): converters.
__global__ __launch_bounds__(256, 2) void k_step(
    const float* __restrict__ Q, const float* __restrict__ R,
    float* __restrict__ Qout, float* __restrict__ Rout,
    unsigned short* __restrict__ Tout,
    const float* __restrict__ X, unsigned short* __restrict__ Xb,
    int first, int last, int convbase, int convend)
{
  __shared__ unsigned short Ah[32*64], Al[32*64], Bh[64*64], Bl[64*64];
  int tid = threadIdx.x, bid = blockIdx.x;
  int qend = last ? 256 : 384;
  if (bid < 256){
    int i0 = (bid >> 4) * 32, j0 = (bid & 15) * 64;
    if (last)
      gtile<false,false,true ,true >(Q, R, R, nullptr, Tout, i0, j0, 1024, 1024, Ah,Al,Bh,Bl, tid);
    else if (first)
      gtile<true ,false,true ,false>(Q, R, R, Rout, nullptr, i0, j0, 1024, 1024, Ah,Al,Bh,Bl, tid);
    else
      gtile<false,false,true ,false>(Q, R, R, Rout, nullptr, i0, j0, 1024, 1024, Ah,Al,Bh,Bl, tid);
  } else if (bid < qend){
    int t = bid - 256;
    int i0 = (t >> 3) * 32, j0 = (t & 7) * 64;
    if (first)
      gtile<true ,true ,false,false>(Q, Q, nullptr, Qout, nullptr, i0, j0, 512, 512, Ah,Al,Bh,Bl, tid);
    else
      gtile<false,false,false,false>(Q, Q, nullptr, Qout, nullptr, i0, j0, 512, 512, Ah,Al,Bh,Bl, tid);
  } else {
    // streaming X converter: granule = 8192 elems
    for (int g = convbase + (bid - qend); g < convend; g += 128){
      const float* src = X + (size_t)g * 8192;
      unsigned short* dst = Xb + (size_t)g * 8192;
      #pragma unroll
      for (int it = 0; it < 8; ++it){
        int p = (tid + it*256) * 4;
        f32x4 v = *reinterpret_cast<const f32x4*>(src + p);
        u16x4 h;
        #pragma unroll
        for (int e = 0; e < 4; ++e) h[e] = f2b(v[e]);
        *reinterpret_cast<u16x4*>(dst + p) = h;
      }
    }
  }
}

// Y[16384][512] = Xb[16384][1024](bf16) * Tt^T.
// BM=BN=128; global_load_lds (linear dest) + source-side granule XOR swizzle,
// fragment reads apply the same XOR -> conflict-free. Double-buffered, 512 blocks.
__global__ __launch_bounds__(256, 2) void k_gemm7(const unsigned short* __restrict__ Xb,
                                                  const unsigned short* __restrict__ Tt,
                                                  float* __restrict__ Y)
{
  __shared__ unsigned short As_[2][128*64];
  __shared__ unsigned short Bs_[2][128*64];
  int tid = threadIdx.x;
  int lane = tid & 63, wave = tid >> 6;
  int wm = wave >> 1, wn = wave & 1;
  int bid = blockIdx.x;
  int wg = (bid & 7) * 64 + (bid >> 3);   // XCD chunks (512 % 8 == 0)
  int m0 = (wg >> 2) * 128;
  int n0 = (wg & 3) * 128;                // n fastest: X panel L2 reuse

  int lrow = lane >> 3;                       // row within 8-row stripe
  int lg   = (lane & 7) ^ lrow;               // pre-swizzled source granule
  f32x4 acc[4][4] = {};

  // dest slot (row = wave*32+it*8+lrow, slot = lane&7) holds global granule
  // (lane&7)^lrow  =>  LDS[row][s] = G[row][s ^ (row&7)]
  #define STAGE(buf, kt)                                                        \
    { _Pragma("unroll")                                                         \
      for (int it = 0; it < 4; ++it){                                           \
        int r = wave*32 + it*8 + lrow;                                          \
        gload16((const void*)(Xb + (size_t)(m0 + r)*1024 + (kt)*64 + lg*8),     \
                (void*)&As_[buf][(wave*256 + it*64)*8]);                        \
        gload16((const void*)(Tt + (size_t)(n0 + r)*1024 + (kt)*64 + lg*8),     \
                (void*)&Bs_[buf][(wave*256 + it*64)*8]);                        \
      } }

  STAGE(0, 0);
  __syncthreads();
  int cur = 0;
  #pragma unroll 1
  for (int kt = 0; kt < 16; ++kt){
    if (kt < 15) STAGE(cur ^ 1, kt + 1);
    const unsigned short* Ab = &As_[cur][0];
    const unsigned short* Bb = &Bs_[cur][0];
    #pragma unroll
    for (int kk = 0; kk < 2; ++kk){
      int gb = kk*4 + (lane >> 4);          // 16B granule within row
      bf16x8 af[4], bfr[4];
      #pragma unroll
      for (int m = 0; m < 4; ++m){
        int row = wm*64 + m*16 + (lane & 15);
        af[m] = *reinterpret_cast<const bf16x8*>((char*)Ab + row*128 + ((gb ^ (row & 7))*16));
      }
      #pragma unroll
      for (int n = 0; n < 4; ++n){
        int row = wn*64 + n*16 + (lane & 15);
        bfr[n] = *reinterpret_cast<const bf16x8*>((char*)Bb + row*128 + ((gb ^ (row & 7))*16));
      }
      #pragma unroll
      for (int m = 0; m < 4; ++m)
        #pragma unroll
        for (int n = 0; n < 4; ++n)
          acc[m][n] = __builtin_amdgcn_mfma_f32_16x16x32_bf16(af[m], bfr[n], acc[m][n], 0,0,0);
    }
    __syncthreads();
    cur ^= 1;
  }
  #undef STAGE

  #pragma unroll
  for (int m = 0; m < 4; ++m)
    #pragma unroll
    for (int n = 0; n < 4; ++n)
      #pragma unroll
      for (int r = 0; r < 4; ++r){
        int row = m0 + wm*64 + m*16 + (lane >> 4)*4 + r;
        int col = n0 + wn*64 + n*16 + (lane & 15);
        Y[(size_t)row*512 + col] = acc[m][n][r];
      }
}

extern "C" void kernel_launch(void* const* d_in, const int* in_sizes, int n_in,
                              void* d_out, int out_size, void* d_ws, size_t ws_size,
                              hipStream_t stream) {
  const float* x = (const float*)d_in[0];   // [16384][1024]
  const float* W = (const float*)d_in[1];   // [512][1024]
  const float* M = (const float*)d_in[2];   // [512][512]
  float* y = (float*)d_out;                 // [16384][512]

  float* Qa = (float*)d_ws;                               // 1 MB
  float* Qb = Qa + 512*512;                               // 1 MB
  float* Ra = Qb + 512*512;                               // 2 MB
  float* Rb = Ra + 512*1024;                              // 2 MB
  unsigned short* Tt = (unsigned short*)(Rb + 512*1024);  // 1 MB  [512][1024] bf16
  unsigned short* Xb = Tt + 512*1024;                     // 32 MB [16384][1024] bf16

  // 4 doublings (Tt = S_16^T W; S_16==S_128 to bf16 precision, rounds 3-6) with
  // X conversion piggybacked: 2048 granules over 4 steps, 128 conv blocks each.
  k_step<<<512, 256, 0, stream>>>(M,  W,  Qa, Ra, nullptr, x, Xb, 1, 0,    0,  512);
  k_step<<<512, 256, 0, stream>>>(Qa, Ra, Qb, Rb, nullptr, x, Xb, 0, 0,  512, 1024);
  k_step<<<512, 256, 0, stream>>>(Qb, Rb, Qa, Ra, nullptr, x, Xb, 0, 0, 1024, 1536);
  k_step<<<384, 256, 0, stream>>>(Qa, Ra, nullptr, nullptr, Tt, x, Xb, 0, 1, 1536, 2048);
  k_gemm7<<<512, 256, 0, stream>>>(Xb, Tt, y);
}

// Round 8
// 70.329 us; speedup vs baseline: 1.3709x; 1.0486x over previous
//
#include <hip/hip_runtime.h>

typedef float f32x4 __attribute__((ext_vector_type(4)));
typedef __bf16 bf16x8 __attribute__((ext_vector_type(8)));
typedef unsigned short u16x4 __attribute__((ext_vector_type(4)));
typedef unsigned short u16x8 __attribute__((ext_vector_type(8)));

__device__ __forceinline__ unsigned short f2b(float f){
  return __builtin_bit_cast(unsigned short, (__bf16)f);
}
__device__ __forceinline__ float b2f(unsigned short u){
  union { unsigned x; float f; } v; v.x = ((unsigned)u) << 16; return v.f;
}
__device__ __forceinline__ void mfma3(f32x4& acc, bf16x8 ah, bf16x8 al, bf16x8 bh, bf16x8 bl){
  acc = __builtin_amdgcn_mfma_f32_16x16x32_bf16(ah, bh, acc, 0, 0, 0);
  acc = __builtin_amdgcn_mfma_f32_16x16x32_bf16(ah, bl, acc, 0, 0, 0);
  acc = __builtin_amdgcn_mfma_f32_16x16x32_bf16(al, bh, acc, 0, 0, 0);
}
__device__ __forceinline__ void gload16(const void* g, void* l){
  __builtin_amdgcn_global_load_lds((const __attribute__((address_space(1))) void*)g,
                                   (__attribute__((address_space(3))) void*)l, 16, 0, 0);
}

// ---------- chain staging loaders/writers (proven rounds 3-7) ----------
template<bool ATR>
__device__ __forceinline__ void loadA(const float* __restrict__ A, int i0, int k0,
                                      int tid, float* aR){
  if (ATR){
    int r32 = tid & 31, kg = tid >> 5;
    #pragma unroll
    for (int q = 0; q < 8; ++q)
      aR[q] = -A[(k0 + kg*8 + q)*512 + i0 + r32];
  } else {
    #pragma unroll
    for (int j = 0; j < 2; ++j){
      int p = tid + j*256;
      int row = p >> 4, kq = p & 15;
      f32x4 v = *reinterpret_cast<const f32x4*>(A + (i0+row)*512 + k0 + kq*4);
      #pragma unroll
      for (int e = 0; e < 4; ++e) aR[j*4+e] = v[e];
    }
  }
}
template<bool ATR>
__device__ __forceinline__ void writeA(const float* aR, int tid,
                                       unsigned short* Ah, unsigned short* Al){
  if (ATR){
    int r32 = tid & 31, kg = tid >> 5;
    #pragma unroll
    for (int q4 = 0; q4 < 2; ++q4){
      u16x4 hi, lo;
      #pragma unroll
      for (int e = 0; e < 4; ++e){
        float f = aR[q4*4+e];
        unsigned short h = f2b(f);
        hi[e] = h; lo[e] = f2b(f - b2f(h));
      }
      int off = r32*128 + (((kg*8 + q4*4)*2) ^ ((r32 & 7) << 4));
      *reinterpret_cast<u16x4*>((char*)Ah + off) = hi;
      *reinterpret_cast<u16x4*>((char*)Al + off) = lo;
    }
  } else {
    #pragma unroll
    for (int j = 0; j < 2; ++j){
      int p = tid + j*256;
      int row = p >> 4, kq = p & 15;
      u16x4 hi, lo;
      #pragma unroll
      for (int e = 0; e < 4; ++e){
        float f = aR[j*4+e];
        unsigned short h = f2b(f);
        hi[e] = h; lo[e] = f2b(f - b2f(h));
      }
      int off = row*128 + ((kq*8) ^ ((row & 7) << 4));
      *reinterpret_cast<u16x4*>((char*)Ah + off) = hi;
      *reinterpret_cast<u16x4*>((char*)Al + off) = lo;
    }
  }
}
template<bool BROWM>
__device__ __forceinline__ void loadB(const float* __restrict__ B, int j0, int k0,
                                      int sb, int tid, float* bR){
  if (BROWM){
    #pragma unroll
    for (int j = 0; j < 4; ++j){
      int p = tid + j*256;
      int n = p >> 4, kq = p & 15;
      f32x4 v = *reinterpret_cast<const f32x4*>(B + (j0+n)*512 + k0 + kq*4);
      #pragma unroll
      for (int e = 0; e < 4; ++e) bR[j*4+e] = -v[e];
    }
  } else {
    int n = tid & 63, kg = tid >> 6;
    #pragma unroll
    for (int q = 0; q < 16; ++q)
      bR[q] = B[(k0 + kg*16 + q)*sb + j0 + n];
  }
}
template<bool BROWM>
__device__ __forceinline__ void writeB(const float* bR, int tid,
                                       unsigned short* Bh, unsigned short* Bl){
  if (BROWM){
    #pragma unroll
    for (int j = 0; j < 4; ++j){
      int p = tid + j*256;
      int n = p >> 4, kq = p & 15;
      u16x4 hi, lo;
      #pragma unroll
      for (int e = 0; e < 4; ++e){
        float f = bR[j*4+e];
        unsigned short h = f2b(f);
        hi[e] = h; lo[e] = f2b(f - b2f(h));
      }
      int off = n*128 + ((kq*8) ^ ((n & 7) << 4));
      *reinterpret_cast<u16x4*>((char*)Bh + off) = hi;
      *reinterpret_cast<u16x4*>((char*)Bl + off) = lo;
    }
  } else {
    int n = tid & 63, kg = tid >> 6;
    #pragma unroll
    for (int q4 = 0; q4 < 4; ++q4){
      u16x4 hi, lo;
      #pragma unroll
      for (int e = 0; e < 4; ++e){
        float f = bR[q4*4+e];
        unsigned short h = f2b(f);
        hi[e] = h; lo[e] = f2b(f - b2f(h));
      }
      int off = n*128 + (((kg*16 + q4*4)*2) ^ ((n & 7) << 4));
      *reinterpret_cast<u16x4*>((char*)Bh + off) = hi;
      *reinterpret_cast<u16x4*>((char*)Bl + off) = lo;
    }
  }
}

// One 32x64 tile of C = [D +] A*B over K=512, split-bf16 (3 MFMAs).
// 3-deep register pipeline: two K-slabs in flight (named sets, rule #20).
template<bool ATR, bool BROWM, bool HASD, bool BFOUT>
__device__ __forceinline__ void gtile(
    const float* __restrict__ A, const float* __restrict__ B,
    const float* __restrict__ D, float* __restrict__ Cf,
    unsigned short* __restrict__ Cb, int i0, int j0, int sb, int so,
    unsigned short* Ah, unsigned short* Al,
    unsigned short* Bh, unsigned short* Bl, int tid)
{
  int lane = tid & 63, wave = tid >> 6;
  int wm = wave >> 1, wn = wave & 1;
  f32x4 acc[2] = {};
  float aR0[8], bR0[16], aR1[8], bR1[16];
  loadA<ATR>(A, i0, 0, tid, aR0);
  loadB<BROWM>(B, j0, 0, sb, tid, bR0);
  loadA<ATR>(A, i0, 64, tid, aR1);
  loadB<BROWM>(B, j0, 64, sb, tid, bR1);

#define CHAIN_MFMA_PHASE                                                   \
    { _Pragma("unroll")                                                    \
      for (int kk = 0; kk < 2; ++kk){                                      \
        int kb = (kk*32 + (lane >> 4)*8) * 2;                              \
        int arow = wm*16 + (lane & 15);                                    \
        int aoff = arow*128 + (kb ^ ((arow & 7) << 4));                    \
        bf16x8 ah = *reinterpret_cast<const bf16x8*>((char*)Ah + aoff);    \
        bf16x8 al = *reinterpret_cast<const bf16x8*>((char*)Al + aoff);    \
        _Pragma("unroll")                                                  \
        for (int n = 0; n < 2; ++n){                                       \
          int brow = wn*32 + n*16 + (lane & 15);                           \
          int boff = brow*128 + (kb ^ ((brow & 7) << 4));                  \
          bf16x8 bh = *reinterpret_cast<const bf16x8*>((char*)Bh + boff);  \
          bf16x8 bl = *reinterpret_cast<const bf16x8*>((char*)Bl + boff);  \
          mfma3(acc[n], ah, al, bh, bl);                                   \
        }                                                                  \
      } }

  #pragma unroll 1
  for (int k0 = 0; k0 < 512; k0 += 128){
    // slab k0 (set 0)
    writeA<ATR>(aR0, tid, Ah, Al);
    writeB<BROWM>(bR0, tid, Bh, Bl);
    __syncthreads();
    if (k0 + 128 < 512){
      loadA<ATR>(A, i0, k0 + 128, tid, aR0);
      loadB<BROWM>(B, j0, k0 + 128, sb, tid, bR0);
    }
    CHAIN_MFMA_PHASE
    __syncthreads();
    // slab k0+64 (set 1)
    writeA<ATR>(aR1, tid, Ah, Al);
    writeB<BROWM>(bR1, tid, Bh, Bl);
    __syncthreads();
    if (k0 + 192 < 512){
      loadA<ATR>(A, i0, k0 + 192, tid, aR1);
      loadB<BROWM>(B, j0, k0 + 192, sb, tid, bR1);
    }
    CHAIN_MFMA_PHASE
    __syncthreads();
  }
#undef CHAIN_MFMA_PHASE

  #pragma unroll
  for (int n = 0; n < 2; ++n)
    #pragma unroll
    for (int r = 0; r < 4; ++r){
      int i = i0 + wm*16 + (lane >> 4)*4 + r;
      int j = j0 + wn*32 + n*16 + (lane & 15);
      float v = acc[n][r];
      if (HASD) v += D[i*so + j];
      if (BFOUT) Cb[i*so + j] = f2b(v);
      else       Cf[i*so + j] = v;
    }
}

// Doubling step + piggybacked X f32->bf16 converter blocks.
// blocks [0,256): R-tiles; [256,qend): Q-tiles; [qend, qend+128): converters.
__global__ __launch_bounds__(256, 2) void k_step(
    const float* __restrict__ Q, const float* __restrict__ R,
    float* __restrict__ Qout, float* __restrict__ Rout,
    unsigned short* __restrict__ Tout,
    const float* __restrict__ X, unsigned short* __restrict__ Xb,
    int first, int last, int convbase, int convend)
{
  __shared__ unsigned short Ah[32*64], Al[32*64], Bh[64*64], Bl[64*64];
  int tid = threadIdx.x, bid = blockIdx.x;
  int qend = last ? 256 : 384;
  if (bid < 256){
    int i0 = (bid >> 4) * 32, j0 = (bid & 15) * 64;
    if (last)
      gtile<false,false,true ,true >(Q, R, R, nullptr, Tout, i0, j0, 1024, 1024, Ah,Al,Bh,Bl, tid);
    else if (first)
      gtile<true ,false,true ,false>(Q, R, R, Rout, nullptr, i0, j0, 1024, 1024, Ah,Al,Bh,Bl, tid);
    else
      gtile<false,false,true ,false>(Q, R, R, Rout, nullptr, i0, j0, 1024, 1024, Ah,Al,Bh,Bl, tid);
  } else if (bid < qend){
    int t = bid - 256;
    int i0 = (t >> 3) * 32, j0 = (t & 7) * 64;
    if (first)
      gtile<true ,true ,false,false>(Q, Q, nullptr, Qout, nullptr, i0, j0, 512, 512, Ah,Al,Bh,Bl, tid);
    else
      gtile<false,false,false,false>(Q, Q, nullptr, Qout, nullptr, i0, j0, 512, 512, Ah,Al,Bh,Bl, tid);
  } else {
    // streaming X converter: granule = 8192 elems
    for (int g = convbase + (bid - qend); g < convend; g += 128){
      const float* src = X + (size_t)g * 8192;
      unsigned short* dst = Xb + (size_t)g * 8192;
      #pragma unroll
      for (int it = 0; it < 8; ++it){
        int p = (tid + it*256) * 4;
        f32x4 v = *reinterpret_cast<const f32x4*>(src + p);
        u16x4 h;
        #pragma unroll
        for (int e = 0; e < 4; ++e) h[e] = f2b(v[e]);
        *reinterpret_cast<u16x4*>(dst + p) = h;
      }
    }
  }
}

// Y[16384][512] = Xb[16384][1024](bf16) * Tt^T.
// BM=BN=128; global_load_lds (linear dest) + source-side granule XOR swizzle,
// fragment reads apply the same XOR -> conflict-free. Double-buffered, 512 blocks.
__global__ __launch_bounds__(256, 2) void k_gemm7(const unsigned short* __restrict__ Xb,
                                                  const unsigned short* __restrict__ Tt,
                                                  float* __restrict__ Y)
{
  __shared__ unsigned short As_[2][128*64];
  __shared__ unsigned short Bs_[2][128*64];
  int tid = threadIdx.x;
  int lane = tid & 63, wave = tid >> 6;
  int wm = wave >> 1, wn = wave & 1;
  int bid = blockIdx.x;
  int wg = (bid & 7) * 64 + (bid >> 3);   // XCD chunks (512 % 8 == 0)
  int m0 = (wg >> 2) * 128;
  int n0 = (wg & 3) * 128;                // n fastest: X panel L2 reuse

  int lrow = lane >> 3;                       // row within 8-row stripe
  int lg   = (lane & 7) ^ lrow;               // pre-swizzled source granule
  f32x4 acc[4][4] = {};

  // dest slot (row = wave*32+it*8+lrow, slot = lane&7) holds global granule
  // (lane&7)^lrow  =>  LDS[row][s] = G[row][s ^ (row&7)]
  #define STAGE(buf, kt)                                                        \
    { _Pragma("unroll")                                                         \
      for (int it = 0; it < 4; ++it){                                           \
        int r = wave*32 + it*8 + lrow;                                          \
        gload16((const void*)(Xb + (size_t)(m0 + r)*1024 + (kt)*64 + lg*8),     \
                (void*)&As_[buf][(wave*256 + it*64)*8]);                        \
        gload16((const void*)(Tt + (size_t)(n0 + r)*1024 + (kt)*64 + lg*8),     \
                (void*)&Bs_[buf][(wave*256 + it*64)*8]);                        \
      } }

  STAGE(0, 0);
  __syncthreads();
  int cur = 0;
  #pragma unroll 1
  for (int kt = 0; kt < 16; ++kt){
    if (kt < 15) STAGE(cur ^ 1, kt + 1);
    const unsigned short* Ab = &As_[cur][0];
    const unsigned short* Bb = &Bs_[cur][0];
    #pragma unroll
    for (int kk = 0; kk < 2; ++kk){
      int gb = kk*4 + (lane >> 4);          // 16B granule within row
      bf16x8 af[4], bfr[4];
      #pragma unroll
      for (int m = 0; m < 4; ++m){
        int row = wm*64 + m*16 + (lane & 15);
        af[m] = *reinterpret_cast<const bf16x8*>((char*)Ab + row*128 + ((gb ^ (row & 7))*16));
      }
      #pragma unroll
      for (int n = 0; n < 4; ++n){
        int row = wn*64 + n*16 + (lane & 15);
        bfr[n] = *reinterpret_cast<const bf16x8*>((char*)Bb + row*128 + ((gb ^ (row & 7))*16));
      }
      #pragma unroll
      for (int m = 0; m < 4; ++m)
        #pragma unroll
        for (int n = 0; n < 4; ++n)
          acc[m][n] = __builtin_amdgcn_mfma_f32_16x16x32_bf16(af[m], bfr[n], acc[m][n], 0,0,0);
    }
    __syncthreads();
    cur ^= 1;
  }
  #undef STAGE

  #pragma unroll
  for (int m = 0; m < 4; ++m)
    #pragma unroll
    for (int n = 0; n < 4; ++n)
      #pragma unroll
      for (int r = 0; r < 4; ++r){
        int row = m0 + wm*64 + m*16 + (lane >> 4)*4 + r;
        int col = n0 + wn*64 + n*16 + (lane & 15);
        Y[(size_t)row*512 + col] = acc[m][n][r];
      }
}

extern "C" void kernel_launch(void* const* d_in, const int* in_sizes, int n_in,
                              void* d_out, int out_size, void* d_ws, size_t ws_size,
                              hipStream_t stream) {
  const float* x = (const float*)d_in[0];   // [16384][1024]
  const float* W = (const float*)d_in[1];   // [512][1024]
  const float* M = (const float*)d_in[2];   // [512][512]
  float* y = (float*)d_out;                 // [16384][512]

  float* Qa = (float*)d_ws;                               // 1 MB
  float* Qb = Qa + 512*512;                               // 1 MB
  float* Ra = Qb + 512*512;                               // 2 MB
  float* Rb = Ra + 512*1024;                              // 2 MB
  unsigned short* Tt = (unsigned short*)(Rb + 512*1024);  // 1 MB  [512][1024] bf16
  unsigned short* Xb = Tt + 512*1024;                     // 32 MB [16384][1024] bf16

  // 4 doublings (Tt = S_16^T W; S_16==S_128 to bf16 precision, rounds 3-7) with
  // X conversion piggybacked: 2048 granules over 4 steps, 128 conv blocks each.
  k_step<<<512, 256, 0, stream>>>(M,  W,  Qa, Ra, nullptr, x, Xb, 1, 0,    0,  512);
  k_step<<<512, 256, 0, stream>>>(Qa, Ra, Qb, Rb, nullptr, x, Xb, 0, 0,  512, 1024);
  k_step<<<512, 256, 0, stream>>>(Qb, Rb, Qa, Ra, nullptr, x, Xb, 0, 0, 1024, 1536);
  k_step<<<384, 256, 0, stream>>>(Qa, Ra, nullptr, nullptr, Tt, x, Xb, 0, 1, 1536, 2048);
  k_gemm7<<<512, 256, 0, stream>>>(Xb, Tt, y);
}